// Round 1
// baseline (47.096 us; speedup 1.0000x reference)
//
#include <hip/hip_runtime.h>

// Time_Pos_Encoding: out[b,s,d] = x[b,s,d] + pe[s,d]
//   rdiv   = 10000^(-2d/D)
//   pe even d: sin(s*rdiv) + sin(101*rdiv)
//   pe odd  d: cos(s*rdiv) + cos(101*rdiv)
// Shapes fixed by the reference: B=8, S=4096, D=1024, f32.

#define TWO_PI   6.283185307179586f
#define INV_2PI  0.15915494309189535f

// __sinf/__cosf are fast (v_sin/v_cos) but the HW takes revolutions and has a
// limited domain; pre-reduce radians to [-pi, pi] so the fast path is valid.
__device__ __forceinline__ float fast_sin(float a) {
    float k = rintf(a * INV_2PI);
    float r = fmaf(-k, TWO_PI, a);   // a - k*2pi, fma-rounded
    return __sinf(r);
}
__device__ __forceinline__ float fast_cos(float a) {
    float k = rintf(a * INV_2PI);
    float r = fmaf(-k, TWO_PI, a);
    return __cosf(r);
}

__global__ __launch_bounds__(256) void tpe_kernel(const float* __restrict__ x,
                                                  float* __restrict__ out) {
    constexpr int S = 4096;
    constexpr int D = 1024;
    constexpr int B = 8;

    const int s  = blockIdx.x;            // one block per sequence row
    const int d0 = threadIdx.x * 4;       // 4 consecutive d per thread

    // exponent coefficient: 2*log2(10000)/D
    constexpr float C = 13.287712379549449f * 2.0f / (float)D;
    const float pos = (float)s;

    float pe[4];
#pragma unroll
    for (int j = 0; j < 4; ++j) {
        const int d = d0 + j;
        const float rdiv = exp2f(-C * (float)d);   // 10000^(-2d/D)
        const float ap = pos * rdiv;
        const float at = 101.0f * rdiv;            // TIME_STEP = 101
        if ((d & 1) == 0)
            pe[j] = fast_sin(ap) + fast_sin(at);
        else
            pe[j] = fast_cos(ap) + fast_cos(at);
    }

    const float4 pev = make_float4(pe[0], pe[1], pe[2], pe[3]);
    const size_t base = (size_t)s * D + (size_t)d0;
    constexpr size_t bstride = (size_t)S * (size_t)D;

#pragma unroll
    for (int b = 0; b < B; ++b) {
        const float4 xv = *reinterpret_cast<const float4*>(x + base + (size_t)b * bstride);
        float4 ov;
        ov.x = xv.x + pev.x;
        ov.y = xv.y + pev.y;
        ov.z = xv.z + pev.z;
        ov.w = xv.w + pev.w;
        *reinterpret_cast<float4*>(out + base + (size_t)b * bstride) = ov;
    }
}

extern "C" void kernel_launch(void* const* d_in, const int* in_sizes, int n_in,
                              void* d_out, int out_size, void* d_ws, size_t ws_size,
                              hipStream_t stream) {
    const float* x = (const float*)d_in[0];
    float* out = (float*)d_out;
    // S=4096 blocks x 256 threads; each thread: 4 d's x 8 batches = 32 elems
    tpe_kernel<<<4096, 256, 0, stream>>>(x, out);
}